// Round 4
// baseline (1866.545 us; speedup 1.0000x reference)
//
#include <hip/hip_runtime.h>
#include <cstddef>

#define NLEV 5
#define TOTROW 21330
#define PTOT 22360   // sum of (H+2)*(W+2)

typedef __bf16 bf16x8 __attribute__((ext_vector_type(8)));
typedef float f32x4 __attribute__((ext_vector_type(4)));
typedef unsigned short ushortx8 __attribute__((ext_vector_type(8)));

struct LvlP {
  int tileoff[6];
  int tilesX[5];
  int H[5], W[5];
  int poff[5], pend[5];
  int roff[6];
  float inv8HW[5];
  float strd[5];
};

static __device__ __forceinline__ unsigned short f2bf(float f) {
  union { float f; unsigned u; } v; v.f = f;
  unsigned r = v.u + 0x7fffu + ((v.u >> 16) & 1u);
  return (unsigned short)(r >> 16);
}
static __device__ __forceinline__ float bf2f(unsigned short h) {
  union { unsigned u; float f; } v; v.u = ((unsigned)h) << 16;
  return v.f;
}
static __device__ __forceinline__ int sel5i(const int* a, int l) {
  int v = a[0];
  v = (l == 1) ? a[1] : v; v = (l == 2) ? a[2] : v;
  v = (l == 3) ? a[3] : v; v = (l == 4) ? a[4] : v;
  return v;
}
static __device__ __forceinline__ float sel5f(const float* a, int l) {
  float v = a[0];
  v = (l == 1) ? a[1] : v; v = (l == 2) ? a[2] : v;
  v = (l == 3) ? a[3] : v; v = (l == 4) ? a[4] : v;
  return v;
}

static __device__ __forceinline__ void gload16(const unsigned short* g, unsigned short* l) {
  __builtin_amdgcn_global_load_lds(
      (const __attribute__((address_space(1))) unsigned int*)(const void*)g,
      (__attribute__((address_space(3))) unsigned int*)(void*)l, 16, 0, 0);
}

// ---------------------------------------------------------------------------
// NCHW fp32 -> padded channel-last bf16: X[n][poff + (y+1)*(W+2)+(x+1)][256]
// ---------------------------------------------------------------------------
__global__ __launch_bounds__(256) void to_chlast(
    const float* __restrict__ feat, unsigned short* __restrict__ X,
    int HW, int W, int poff)
{
  const int n = blockIdx.y >> 2, cb = blockIdx.y & 3;
  const int p0 = blockIdx.x * 64;
  __shared__ unsigned short s[64][72];
  const int t = threadIdx.x;
  const int pl = t & 63, ci = t >> 6;
  const float* src = feat + ((size_t)(n * 256 + cb * 64)) * HW;
#pragma unroll
  for (int i = 0; i < 16; ++i) {
    const int c = ci + i * 4;
    const int p = p0 + pl;
    float v = (p < HW) ? src[(size_t)c * HW + p] : 0.f;
    s[c][pl] = f2bf(v);
  }
  __syncthreads();
  const int cl = t & 63, pi = t >> 6;
#pragma unroll
  for (int i = 0; i < 16; ++i) {
    const int p = p0 + pi + i * 4;
    if (p < HW) {
      const int y = p / W, x = p - y * W;
      const size_t dst = ((size_t)n * PTOT + poff + (y + 1) * (W + 2) + (x + 1)) * 256
                       + cb * 64 + cl;
      X[dst] = s[cl][pi + i * 4];
    }
  }
}

// ---------------------------------------------------------------------------
// tower weights fp32 [4][256][256][3][3] -> bf16 [layer][ch8][tap9][q4][oc256][8]
// ---------------------------------------------------------------------------
__global__ __launch_bounds__(256) void prep_tower_w(
    const float* __restrict__ cls_w, const float* __restrict__ box_w,
    unsigned short* __restrict__ wtC, unsigned short* __restrict__ wtR)
{
  const long e = (long)blockIdx.x * 256 + threadIdx.x;
  if (e >= 2359296L) return;
  const int j = (int)(e & 7);
  long r = e >> 3;
  const int oc = (int)(r & 255); r >>= 8;
  const int q = (int)(r & 3); r >>= 2;
  const int tap = (int)(r % 9);
  const long s = r / 9;
  const int ch = (int)(s & 7);
  const int layer = (int)(s >> 3);
  const int ic = ch * 32 + q * 8 + j;
  const long src = (((long)layer * 256 + oc) * 256 + ic) * 9 + tap;
  wtC[e] = f2bf(cls_w[src]);
  wtR[e] = f2bf(box_w[src]);
}

// ---------------------------------------------------------------------------
// head weights -> bf16 [ch16][tap9][q4][oc128][8]; k = ch*32+q*8+j in [0,512)
// k<256: cls-tower input (score); k>=256: box-tower input (ctr/pred)
// ---------------------------------------------------------------------------
__global__ __launch_bounds__(256) void prep_head_w(
    const float* __restrict__ sw, const float* __restrict__ sb,
    const float* __restrict__ cw, const float* __restrict__ cb,
    const float* __restrict__ pw, const float* __restrict__ pb,
    unsigned short* __restrict__ wth, float* __restrict__ bh)
{
  const long e = (long)blockIdx.x * 256 + threadIdx.x;
  if (e < 589824L) {
    const int j = (int)(e & 7);
    long r = e >> 3;
    const int oc = (int)(r & 127); r >>= 7;
    const int q = (int)(r & 3); r >>= 2;
    const int tap = (int)(r % 9);
    const int ch = (int)(r / 9);
    const int k = ch * 32 + q * 8 + j;
    float v = 0.f;
    if (oc < 80) { if (k < 256) v = sw[((long)(oc * 256 + k)) * 9 + tap]; }
    else if (oc == 80) { if (k >= 256) v = cw[(long)(k - 256) * 9 + tap]; }
    else if (oc < 85) { if (k >= 256) v = pw[((long)((oc - 81) * 256 + (k - 256))) * 9 + tap]; }
    wth[e] = f2bf(v);
  }
  if (blockIdx.x == 0) {
    const int t = threadIdx.x;
    if (t < 128) bh[t] = (t < 80) ? sb[t] : (t == 80) ? cb[0] : (t < 85) ? pb[t - 81] : 0.f;
  }
}

// ---------------------------------------------------------------------------
// MFMA implicit-GEMM 3x3 conv, all levels in one dispatch.
// Tile M=192 (16x x 12y), N=64 oc. A: LDS double-buffered via global_load_lds
// (one barrier per 32-ic chunk). B: direct global->VGPR with 1-tap prefetch.
// kimg=1: towers, z=tower*2+n, K=256. kimg=2: head, z=n, K=512 (cls||box).
// ---------------------------------------------------------------------------
__global__ __launch_bounds__(256, 4) void conv_mfma(
    const unsigned short* __restrict__ inC, const unsigned short* __restrict__ inR,
    unsigned short* __restrict__ outC, unsigned short* __restrict__ outR,
    const unsigned short* __restrict__ wtC, const unsigned short* __restrict__ wtR,
    const float* __restrict__ bsC, const float* __restrict__ bsR,
    float* __restrict__ stats, LvlP P, int kimg, int octot)
{
  const int bt = blockIdx.x;
  const int l = (bt >= P.tileoff[1]) + (bt >= P.tileoff[2])
              + (bt >= P.tileoff[3]) + (bt >= P.tileoff[4]);
  const int t = bt - sel5i(P.tileoff, l);
  const int tX = sel5i(P.tilesX, l);
  const int ty = t / tX, tx = t - ty * tX;
  const int x0 = tx << 4, y0 = ty * 12;
  const int H = sel5i(P.H, l), W = sel5i(P.W, l);
  const int W2 = W + 2;
  const int pbase = sel5i(P.poff, l);
  const int pmax = sel5i(P.pend, l) - 1;
  const int rbase = sel5i(P.roff, l);
  const int oc0 = blockIdx.y << 6;
  const int z = blockIdx.z;

  const unsigned short *A0, *A1, *wt;
  const float* bs; unsigned short* out;
  if (kimg == 1) {
    const int tower = z >> 1, n = z & 1;
    const unsigned short* a = (tower ? inR : inC) + (size_t)n * PTOT * 256;
    A0 = a; A1 = a;
    wt = tower ? wtR : wtC;
    bs = tower ? bsR : bsC;
    out = (tower ? outR : outC) + (size_t)n * TOTROW * octot;
  } else {
    A0 = inC + (size_t)z * PTOT * 256;
    A1 = inR + (size_t)z * PTOT * 256;
    wt = wtC; bs = bsC;
    out = outC + (size_t)z * TOTROW * octot;
  }
  const int nchunk = kimg << 3;
  const int ntap = nchunk * 9;

  __shared__ unsigned short sA[2][8192];   // 2 x 16 KB, [pos252][part4][8ic]

  const int tid = threadIdx.x;
  const int wv = tid >> 6, lane = tid & 63;
  const int t15 = lane & 15, q = lane >> 4;

  // per-lane A-staging source offsets (in shorts) for this wave's 4 insts
  unsigned aoff[4];
#pragma unroll
  for (int it = 0; it < 4; ++it) {
    const int inst = wv + it * 4;
    const int item = (inst << 6) + lane;
    int pos = item >> 2; pos = (pos > 251) ? 251 : pos;
    const int part = item & 3;
    const int hy = pos / 18, hx = pos - hy * 18;
    int pidx = pbase + (y0 + hy) * W2 + (x0 + hx);
    pidx = (pidx > pmax) ? pmax : pidx;
    aoff[it] = ((unsigned)pidx << 8) + (part << 3);
  }

  // per-lane B pointer: [chtap][q][oc][8j]
  const unsigned short* wbL = wt + ((size_t)(q * octot + oc0 + t15) << 3);
  const unsigned chtapstride = (unsigned)octot << 5;   // 4*octot*8 shorts

  f32x4 acc[3][4];
#pragma unroll
  for (int g = 0; g < 4; ++g) {
    const float b = bs[oc0 + g * 16 + t15];
#pragma unroll
    for (int f = 0; f < 3; ++f) {
      acc[f][g][0] = b; acc[f][g][1] = b; acc[f][g][2] = b; acc[f][g][3] = b;
    }
  }

  // stage chunk 0, preload B(0,0)
  {
    const unsigned icb = 0;
#pragma unroll
    for (int it = 0; it < 4; ++it)
      gload16(A0 + aoff[it] + icb, &sA[0][(wv + it * 4) << 9]);
  }
  bf16x8 bcur[4];
#pragma unroll
  for (int g = 0; g < 4; ++g) bcur[g] = *(const bf16x8*)(wbL + g * 128);
  __syncthreads();

  for (int ch = 0; ch < nchunk; ++ch) {
    if (ch + 1 < nchunk) {
      const unsigned short* Ap = (ch + 1 < 8) ? A0 : A1;
      const unsigned icb = ((ch + 1) & 7) << 5;
      unsigned short* dst = sA[(ch + 1) & 1];
#pragma unroll
      for (int it = 0; it < 4; ++it)
        gload16(Ap + aoff[it] + icb, dst + ((wv + it * 4) << 9));
    }
    const unsigned short* sAb = sA[ch & 1];
#pragma unroll
    for (int tap = 0; tap < 9; ++tap) {
      const int nchtap = ch * 9 + tap + 1;
      bf16x8 bnxt[4];
      const bool have_next = (nchtap < ntap);
      if (have_next) {
        const unsigned short* pn = wbL + (size_t)nchtap * chtapstride;
#pragma unroll
        for (int g = 0; g < 4; ++g) bnxt[g] = *(const bf16x8*)(pn + g * 128);
      }
      const int ky = tap / 3, kx = tap - ky * 3;
#pragma unroll
      for (int f = 0; f < 3; ++f) {
        const int pos = (wv * 3 + f + ky) * 18 + t15 + kx;
        const bf16x8 a = *(const bf16x8*)(sAb + ((pos * 4 + q) << 3));
#pragma unroll
        for (int g = 0; g < 4; ++g)
          acc[f][g] = __builtin_amdgcn_mfma_f32_16x16x32_bf16(a, bcur[g], acc[f][g], 0, 0, 0);
      }
      if (have_next) {
#pragma unroll
        for (int g = 0; g < 4; ++g) bcur[g] = bnxt[g];
      }
    }
    __syncthreads();
  }

  // epilogue: store bf16 + fused GN partial stats
#pragma unroll
  for (int g = 0; g < 4; ++g) {
    const int oc = oc0 + g * 16 + t15;
    float s = 0.f, ss = 0.f;
#pragma unroll
    for (int f = 0; f < 3; ++f) {
      const int gy = y0 + wv * 3 + f;
#pragma unroll
      for (int rg = 0; rg < 4; ++rg) {
        const int gx = x0 + q * 4 + rg;
        if (gy < H && gx < W) {
          const float v = acc[f][g][rg];
          out[(size_t)(rbase + gy * W + gx) * octot + oc] = f2bf(v);
          s += v; ss += v * v;
        }
      }
    }
    if (stats) {
      s += __shfl_xor(s, 1);  ss += __shfl_xor(ss, 1);
      s += __shfl_xor(s, 2);  ss += __shfl_xor(ss, 2);
      s += __shfl_xor(s, 4);  ss += __shfl_xor(ss, 4);
      s += __shfl_xor(s, 16); ss += __shfl_xor(ss, 16);
      s += __shfl_xor(s, 32); ss += __shfl_xor(ss, 32);
      if ((lane & 55) == 0) {   // lanes 0 and 8 hold the two GN groups of this g
        float* st = stats + (((size_t)l * 4 + z) * 32 + (oc >> 3)) * 2;
        atomicAdd(st, s); atomicAdd(st + 1, ss);
      }
    }
  }
}

// ---------------------------------------------------------------------------
// GN apply + ReLU, merged levels: reads unpadded Y, writes padded X interior.
// grid: (ceil(21330*32/256), 4 imgs)
// ---------------------------------------------------------------------------
__global__ __launch_bounds__(256) void gn_apply(
    const unsigned short* __restrict__ Yc, const unsigned short* __restrict__ Yr,
    unsigned short* __restrict__ Xc, unsigned short* __restrict__ Xr,
    const float* __restrict__ stats,
    const float* __restrict__ gwC, const float* __restrict__ gbC,
    const float* __restrict__ gwR, const float* __restrict__ gbR, LvlP P)
{
  const int img = blockIdx.y;
  const int tower = img >> 1, n = img & 1;
  const int e = blockIdx.x * 256 + threadIdx.x;
  const int pos = e >> 5;
  const int g = e & 31;
  if (pos >= TOTROW) return;
  const int l = (pos >= P.roff[1]) + (pos >= P.roff[2]) + (pos >= P.roff[3]) + (pos >= P.roff[4]);
  const int W = sel5i(P.W, l);
  const int local = pos - sel5i(P.roff, l);
  const int y = local / W, x = local - y * W;
  const size_t dst = ((size_t)n * PTOT + sel5i(P.poff, l) + (y + 1) * (W + 2) + (x + 1)) * 256 + g * 8;
  const size_t srco = ((size_t)n * TOTROW + pos) * 256 + g * 8;
  const unsigned short* Y = (tower ? Yr : Yc) + srco;
  unsigned short* X = (tower ? Xr : Xc) + dst;
  const float* gw = (tower ? gwR : gwC) + g * 8;
  const float* gb = (tower ? gbR : gbC) + g * 8;
  const float* st = stats + (((size_t)l * 4 + img) * 32 + g) * 2;
  const float inv = sel5f(P.inv8HW, l);
  const float m = st[0] * inv;
  const float var = st[1] * inv - m * m;
  const float rs = rsqrtf(var + 1e-5f);
  ushortx8 yv = *(const ushortx8*)Y;
  ushortx8 xv;
#pragma unroll
  for (int j = 0; j < 8; ++j) {
    const float yj = bf2f(yv[j]);
    const float v = (yj - m) * rs * gw[j] + gb[j];
    xv[j] = f2bf(fmaxf(v, 0.f));
  }
  *(ushortx8*)X = xv;
}

// ---------------------------------------------------------------------------
// Head epilogue, merged levels: Yh [n][21330][128] bf16 -> out [n][21330][84]
// ---------------------------------------------------------------------------
__global__ __launch_bounds__(256) void head_epi(
    const unsigned short* __restrict__ Yh, float* __restrict__ out,
    const float* __restrict__ scales, LvlP P)
{
  const int n = blockIdx.y;
  const int e = blockIdx.x * 256 + threadIdx.x;
  if (e >= TOTROW * 84) return;
  const int pos = e / 84;
  const int j = e - pos * 84;
  const int l = (pos >= P.roff[1]) + (pos >= P.roff[2]) + (pos >= P.roff[3]) + (pos >= P.roff[4]);
  const unsigned short* yp = Yh + ((size_t)n * TOTROW + pos) * 128;
  float v;
  if (j < 80) {
    const float lg = bf2f(yp[j]);
    const float ct = bf2f(yp[80]);
    v = (1.f / (1.f + __expf(-lg))) * (1.f / (1.f + __expf(-ct)));
  } else {
    const int d = j - 80;
    const float stride = sel5f(P.strd, l);
    const int W = sel5i(P.W, l);
    const int local = pos - sel5i(P.roff, l);
    const int gy = local / W, gx = local - gy * W;
    const float pv = bf2f(yp[81 + d]);
    const float rg = fmaxf(pv * scales[l], 0.f) * stride;
    const float sx = gx * stride, sy = gy * stride;
    v = (d == 0) ? sx - rg : (d == 1) ? sy - rg : (d == 2) ? sx + rg : sy + rg;
  }
  out[((size_t)n * TOTROW + pos) * 84 + j] = v;
}

// ---------------------------------------------------------------------------
extern "C" void kernel_launch(void* const* d_in, const int* in_sizes, int n_in,
                              void* d_out, int out_size, void* d_ws, size_t ws_size,
                              hipStream_t stream)
{
  (void)in_sizes; (void)n_in; (void)out_size; (void)ws_size;

  const float* feats[5];
  for (int l = 0; l < 5; ++l) feats[l] = (const float*)d_in[l];
  const float* cls_w  = (const float*)d_in[5];
  const float* cls_b  = (const float*)d_in[6];
  const float* cls_gw = (const float*)d_in[7];
  const float* cls_gb = (const float*)d_in[8];
  const float* box_w  = (const float*)d_in[9];
  const float* box_b  = (const float*)d_in[10];
  const float* box_gw = (const float*)d_in[11];
  const float* box_gb = (const float*)d_in[12];
  const float* score_w = (const float*)d_in[13];
  const float* score_b = (const float*)d_in[14];
  const float* pred_w  = (const float*)d_in[15];
  const float* pred_b  = (const float*)d_in[16];
  const float* ctr_w   = (const float*)d_in[17];
  const float* ctr_b   = (const float*)d_in[18];
  const float* scales  = (const float*)d_in[19];
  float* out = (float*)d_out;

  static const int Hs[5] = {100, 50, 25, 13, 7};
  static const int Ws[5] = {160, 80, 40, 20, 10};
  LvlP P;
  {
    static const int to[6] = {0, 90, 115, 124, 128, 129};
    static const int tX[5] = {10, 5, 3, 2, 1};
    static const int po[5] = {0, 16524, 20788, 21922, 22252};
    static const int pe[5] = {16524, 20788, 21922, 22252, 22360};
    static const int ro[6] = {0, 16000, 20000, 21000, 21260, 21330};
    for (int i = 0; i < 6; ++i) { P.tileoff[i] = to[i]; P.roff[i] = ro[i]; }
    for (int i = 0; i < 5; ++i) {
      P.tilesX[i] = tX[i]; P.H[i] = Hs[i]; P.W[i] = Ws[i];
      P.poff[i] = po[i]; P.pend[i] = pe[i];
      P.inv8HW[i] = 1.f / (8.f * Hs[i] * Ws[i]);
      P.strd[i] = (float)(8 << i);
    }
  }

  char* p = (char*)d_ws;
  auto alloc = [&](size_t bytes) {
    char* r = p;
    p += (bytes + 255) & ~(size_t)255;
    return r;
  };
  const size_t XPAD = (size_t)2 * PTOT * 256 * 2;
  const size_t YSZ  = (size_t)2 * TOTROW * 256 * 2;
  unsigned short* Xf  = (unsigned short*)alloc(XPAD);
  unsigned short* Xc  = (unsigned short*)alloc(XPAD);
  unsigned short* Xr  = (unsigned short*)alloc(XPAD);
  unsigned short* Yc  = (unsigned short*)alloc(YSZ);
  unsigned short* Yr  = (unsigned short*)alloc(YSZ);
  unsigned short* Yh  = (unsigned short*)alloc((size_t)2 * TOTROW * 128 * 2);
  unsigned short* wtC = (unsigned short*)alloc(4718592);
  unsigned short* wtR = (unsigned short*)alloc(4718592);
  unsigned short* wth = (unsigned short*)alloc(1179648);
  float* bh    = (float*)alloc(512);
  float* stats = (float*)alloc(4 * 5 * 4 * 32 * 2 * sizeof(float));

  hipMemsetAsync(Xf, 0, XPAD, stream);
  hipMemsetAsync(Xc, 0, XPAD, stream);
  hipMemsetAsync(Xr, 0, XPAD, stream);
  hipMemsetAsync(stats, 0, 4 * 5 * 4 * 32 * 2 * sizeof(float), stream);

  prep_tower_w<<<9216, 256, 0, stream>>>(cls_w, box_w, wtC, wtR);
  prep_head_w<<<2304, 256, 0, stream>>>(score_w, score_b, ctr_w, ctr_b,
                                        pred_w, pred_b, wth, bh);
  for (int l = 0; l < 5; ++l) {
    const int HW = Hs[l] * Ws[l];
    to_chlast<<<dim3((HW + 63) / 64, 8), 256, 0, stream>>>(
        feats[l], Xf, HW, Ws[l], P.poff[l]);
  }

  for (int i = 0; i < 4; ++i) {
    const unsigned short* ic_ = (i == 0) ? Xf : Xc;
    const unsigned short* ir_ = (i == 0) ? Xf : Xr;
    float* st = stats + (size_t)i * 5 * 4 * 32 * 2;
    conv_mfma<<<dim3(129, 4, 4), 256, 0, stream>>>(
        ic_, ir_, Yc, Yr,
        wtC + (size_t)i * 589824, wtR + (size_t)i * 589824,
        cls_b + i * 256, box_b + i * 256, st, P, 1, 256);
    gn_apply<<<dim3((TOTROW * 32 + 255) / 256, 4), 256, 0, stream>>>(
        Yc, Yr, Xc, Xr, st,
        cls_gw + i * 256, cls_gb + i * 256,
        box_gw + i * 256, box_gb + i * 256, P);
  }

  conv_mfma<<<dim3(129, 2, 2), 256, 0, stream>>>(
      Xc, Xr, Yh, nullptr, wth, nullptr, bh, nullptr, nullptr, P, 2, 128);
  head_epi<<<dim3((TOTROW * 84 + 255) / 256, 2), 256, 0, stream>>>(
      Yh, out, scales, P);
}

// Round 5
// 944.828 us; speedup vs baseline: 1.9755x; 1.9755x over previous
//
#include <hip/hip_runtime.h>
#include <cstddef>

#define NLEV 5
#define TOTROW 21330
#define PTOT 22360   // sum of (H+2)*(W+2)

typedef __bf16 bf16x8 __attribute__((ext_vector_type(8)));
typedef float f32x4 __attribute__((ext_vector_type(4)));
typedef unsigned short ushortx8 __attribute__((ext_vector_type(8)));

struct LvlP {
  int tileoff[6];
  int tilesX[5];
  int H[5], W[5];
  int poff[5], pend[5];
  int roff[6];
  float inv8HW[5];
  float strd[5];
};

static __device__ __forceinline__ unsigned short f2bf(float f) {
  union { float f; unsigned u; } v; v.f = f;
  unsigned r = v.u + 0x7fffu + ((v.u >> 16) & 1u);
  return (unsigned short)(r >> 16);
}
static __device__ __forceinline__ float bf2f(unsigned short h) {
  union { unsigned u; float f; } v; v.u = ((unsigned)h) << 16;
  return v.f;
}
static __device__ __forceinline__ int sel5i(const int* a, int l) {
  int v = a[0];
  v = (l == 1) ? a[1] : v; v = (l == 2) ? a[2] : v;
  v = (l == 3) ? a[3] : v; v = (l == 4) ? a[4] : v;
  return v;
}
static __device__ __forceinline__ float sel5f(const float* a, int l) {
  float v = a[0];
  v = (l == 1) ? a[1] : v; v = (l == 2) ? a[2] : v;
  v = (l == 3) ? a[3] : v; v = (l == 4) ? a[4] : v;
  return v;
}

static __device__ __forceinline__ void gload16(const unsigned short* g, unsigned short* l) {
  __builtin_amdgcn_global_load_lds(
      (const __attribute__((address_space(1))) unsigned int*)(const void*)g,
      (__attribute__((address_space(3))) unsigned int*)(void*)l, 16, 0, 0);
}

// ---------------------------------------------------------------------------
// NCHW fp32 -> padded channel-last bf16: X[n][poff + (y+1)*(W+2)+(x+1)][256]
// ---------------------------------------------------------------------------
__global__ __launch_bounds__(256) void to_chlast(
    const float* __restrict__ feat, unsigned short* __restrict__ X,
    int HW, int W, int poff)
{
  const int n = blockIdx.y >> 2, cb = blockIdx.y & 3;
  const int p0 = blockIdx.x * 64;
  __shared__ unsigned short s[64][72];
  const int t = threadIdx.x;
  const int pl = t & 63, ci = t >> 6;
  const float* src = feat + ((size_t)(n * 256 + cb * 64)) * HW;
#pragma unroll
  for (int i = 0; i < 16; ++i) {
    const int c = ci + i * 4;
    const int p = p0 + pl;
    float v = (p < HW) ? src[(size_t)c * HW + p] : 0.f;
    s[c][pl] = f2bf(v);
  }
  __syncthreads();
  const int cl = t & 63, pi = t >> 6;
#pragma unroll
  for (int i = 0; i < 16; ++i) {
    const int p = p0 + pi + i * 4;
    if (p < HW) {
      const int y = p / W, x = p - y * W;
      const size_t dst = ((size_t)n * PTOT + poff + (y + 1) * (W + 2) + (x + 1)) * 256
                       + cb * 64 + cl;
      X[dst] = s[cl][pi + i * 4];
    }
  }
}

// ---------------------------------------------------------------------------
// tower weights fp32 [4][256][256][3][3] -> bf16 [layer][ch8][tap9][q4][oc256][8]
// ---------------------------------------------------------------------------
__global__ __launch_bounds__(256) void prep_tower_w(
    const float* __restrict__ cls_w, const float* __restrict__ box_w,
    unsigned short* __restrict__ wtC, unsigned short* __restrict__ wtR)
{
  const long e = (long)blockIdx.x * 256 + threadIdx.x;
  if (e >= 2359296L) return;
  const int j = (int)(e & 7);
  long r = e >> 3;
  const int oc = (int)(r & 255); r >>= 8;
  const int q = (int)(r & 3); r >>= 2;
  const int tap = (int)(r % 9);
  const long s = r / 9;
  const int ch = (int)(s & 7);
  const int layer = (int)(s >> 3);
  const int ic = ch * 32 + q * 8 + j;
  const long src = (((long)layer * 256 + oc) * 256 + ic) * 9 + tap;
  wtC[e] = f2bf(cls_w[src]);
  wtR[e] = f2bf(box_w[src]);
}

// ---------------------------------------------------------------------------
// head weights -> bf16 [ch16][tap9][q4][oc128][8]; k = ch*32+q*8+j in [0,512)
// k<256: cls-tower input (score); k>=256: box-tower input (ctr/pred)
// ---------------------------------------------------------------------------
__global__ __launch_bounds__(256) void prep_head_w(
    const float* __restrict__ sw, const float* __restrict__ sb,
    const float* __restrict__ cw, const float* __restrict__ cb,
    const float* __restrict__ pw, const float* __restrict__ pb,
    unsigned short* __restrict__ wth, float* __restrict__ bh)
{
  const long e = (long)blockIdx.x * 256 + threadIdx.x;
  if (e < 589824L) {
    const int j = (int)(e & 7);
    long r = e >> 3;
    const int oc = (int)(r & 127); r >>= 7;
    const int q = (int)(r & 3); r >>= 2;
    const int tap = (int)(r % 9);
    const int ch = (int)(r / 9);
    const int k = ch * 32 + q * 8 + j;
    float v = 0.f;
    if (oc < 80) { if (k < 256) v = sw[((long)(oc * 256 + k)) * 9 + tap]; }
    else if (oc == 80) { if (k >= 256) v = cw[(long)(k - 256) * 9 + tap]; }
    else if (oc < 85) { if (k >= 256) v = pw[((long)((oc - 81) * 256 + (k - 256))) * 9 + tap]; }
    wth[e] = f2bf(v);
  }
  if (blockIdx.x == 0) {
    const int t = threadIdx.x;
    if (t < 128) bh[t] = (t < 80) ? sb[t] : (t == 80) ? cb[0] : (t < 85) ? pb[t - 81] : 0.f;
  }
}

// ---------------------------------------------------------------------------
// MFMA implicit-GEMM 3x3 conv, all levels in one dispatch.
// Block tile M=384 (32x x 12y), N=64 oc. Wave: f=6 (3 rows x 2 col-halves),
// g=4 -> 24 MFMA/tap, acc=96 VGPR. A+B staged to LDS via global_load_lds
// (16B), 2 barriers per 32-ic chunk. LDS 68 KB -> 2 blocks/CU.
// kimg=1: towers, z=tower*2+n, K=256. kimg=2: head, z=n, K=512 (cls||box).
// ---------------------------------------------------------------------------
__global__ __launch_bounds__(256, 2) void conv_mfma(
    const unsigned short* __restrict__ inC, const unsigned short* __restrict__ inR,
    unsigned short* __restrict__ outC, unsigned short* __restrict__ outR,
    const unsigned short* __restrict__ wtC, const unsigned short* __restrict__ wtR,
    const float* __restrict__ bsC, const float* __restrict__ bsR,
    float* __restrict__ stats, LvlP P, int kimg, int octot)
{
  const int bt = blockIdx.x;
  const int l = (bt >= P.tileoff[1]) + (bt >= P.tileoff[2])
              + (bt >= P.tileoff[3]) + (bt >= P.tileoff[4]);
  const int t = bt - sel5i(P.tileoff, l);
  const int tX = sel5i(P.tilesX, l);
  const int ty = t / tX, tx = t - ty * tX;
  const int x0 = tx << 5, y0 = ty * 12;
  const int H = sel5i(P.H, l), W = sel5i(P.W, l);
  const int W2 = W + 2;
  const int pbase = sel5i(P.poff, l);
  const int pmax = sel5i(P.pend, l) - 1;
  const int rbase = sel5i(P.roff, l);
  const int oc0 = blockIdx.y << 6;
  const int z = blockIdx.z;

  const unsigned short *A0, *A1, *wt;
  const float* bs; unsigned short* out;
  if (kimg == 1) {
    const int tower = z >> 1, n = z & 1;
    const unsigned short* a = (tower ? inR : inC) + (size_t)n * PTOT * 256;
    A0 = a; A1 = a;
    wt = tower ? wtR : wtC;
    bs = tower ? bsR : bsC;
    out = (tower ? outR : outC) + (size_t)n * TOTROW * octot;
  } else {
    A0 = inC + (size_t)z * PTOT * 256;
    A1 = inR + (size_t)z * PTOT * 256;
    wt = wtC; bs = bsC;
    out = outC + (size_t)z * TOTROW * octot;
  }
  const int nchunk = kimg << 3;

  __shared__ unsigned short sA[512 * 32];   // [pos 476(+pad)][part4][8ic]  32 KB
  __shared__ unsigned short sB[36 * 512];   // [tap][q][oc64][8ic]          36 KB

  const int tid = threadIdx.x;
  const int wv = tid >> 6, lane = tid & 63;
  const int t15 = lane & 15, q = lane >> 4;

  // per-lane A-staging source offsets (in shorts): 8 instrs/wave, 32 total
  unsigned aoff[8];
#pragma unroll
  for (int it = 0; it < 8; ++it) {
    const int inst = wv + it * 4;
    const int item = (inst << 6) + lane;
    int pos = item >> 2; pos = (pos > 475) ? 475 : pos;
    const int part = item & 3;
    const int hy = pos / 34, hx = pos - hy * 34;
    int pidx = pbase + (y0 + hy) * W2 + (x0 + hx);
    pidx = (pidx > pmax) ? pmax : pidx;
    aoff[it] = ((unsigned)pidx << 8) + (part << 3);
  }

  f32x4 acc[6][4];
#pragma unroll
  for (int g = 0; g < 4; ++g) {
    const float b = bs[oc0 + g * 16 + t15];
#pragma unroll
    for (int f = 0; f < 6; ++f) {
      acc[f][g][0] = b; acc[f][g][1] = b; acc[f][g][2] = b; acc[f][g][3] = b;
    }
  }

  for (int ch = 0; ch < nchunk; ++ch) {
    const unsigned short* Ap = (ch < 8) ? A0 : A1;
    const unsigned icb = (ch & 7) << 5;
    __syncthreads();
    // A stage: 32 wave-instructions of 64 lanes x 16 B
#pragma unroll
    for (int it = 0; it < 8; ++it)
      gload16(Ap + aoff[it] + icb, sA + ((wv + it * 4) << 9));
    // B stage: 36 wave-instructions, fully contiguous 1 KB each
    const unsigned short* wb = wt + ((size_t)(ch * 36) * octot + oc0) * 8 + (lane << 3);
#pragma unroll
    for (int it = 0; it < 9; ++it)
      gload16(wb + (size_t)(wv + it * 4) * octot * 8, sB + ((wv + it * 4) << 9));
    __syncthreads();

#pragma unroll
    for (int ky = 0; ky < 3; ++ky) {
#pragma unroll
      for (int kx = 0; kx < 3; ++kx) {
        const int tap = ky * 3 + kx;
        bf16x8 b[4];
#pragma unroll
        for (int g = 0; g < 4; ++g)
          b[g] = *(const bf16x8*)(sB + ((((tap * 4 + q) << 6) + g * 16 + t15) << 3));
#pragma unroll
        for (int f = 0; f < 6; ++f) {
          const int fr = f >> 1, fc = f & 1;
          const int pos = (wv * 3 + fr + ky) * 34 + fc * 16 + t15 + kx;
          const bf16x8 a = *(const bf16x8*)(sA + ((pos * 4 + q) << 3));
#pragma unroll
          for (int g = 0; g < 4; ++g)
            acc[f][g] = __builtin_amdgcn_mfma_f32_16x16x32_bf16(a, b[g], acc[f][g], 0, 0, 0);
        }
      }
    }
  }

  // epilogue: store bf16 + fused GN partial stats
#pragma unroll
  for (int g = 0; g < 4; ++g) {
    const int oc = oc0 + g * 16 + t15;
    float s = 0.f, ss = 0.f;
#pragma unroll
    for (int f = 0; f < 6; ++f) {
      const int fr = f >> 1, fc = f & 1;
      const int gy = y0 + wv * 3 + fr;
#pragma unroll
      for (int rg = 0; rg < 4; ++rg) {
        const int gx = x0 + fc * 16 + q * 4 + rg;
        if (gy < H && gx < W) {
          const float v = acc[f][g][rg];
          out[(size_t)(rbase + gy * W + gx) * octot + oc] = f2bf(v);
          s += v; ss += v * v;
        }
      }
    }
    if (stats) {
      s += __shfl_xor(s, 1);  ss += __shfl_xor(ss, 1);
      s += __shfl_xor(s, 2);  ss += __shfl_xor(ss, 2);
      s += __shfl_xor(s, 4);  ss += __shfl_xor(ss, 4);
      s += __shfl_xor(s, 16); ss += __shfl_xor(ss, 16);
      s += __shfl_xor(s, 32); ss += __shfl_xor(ss, 32);
      if ((lane & 55) == 0) {   // lanes 0 and 8 hold the two GN groups of this g
        float* st = stats + (((size_t)l * 4 + z) * 32 + (oc >> 3)) * 2;
        atomicAdd(st, s); atomicAdd(st + 1, ss);
      }
    }
  }
}

// ---------------------------------------------------------------------------
// GN apply + ReLU, merged levels: reads unpadded Y, writes padded X interior.
// grid: (ceil(21330*32/256), 4 imgs)
// ---------------------------------------------------------------------------
__global__ __launch_bounds__(256) void gn_apply(
    const unsigned short* __restrict__ Yc, const unsigned short* __restrict__ Yr,
    unsigned short* __restrict__ Xc, unsigned short* __restrict__ Xr,
    const float* __restrict__ stats,
    const float* __restrict__ gwC, const float* __restrict__ gbC,
    const float* __restrict__ gwR, const float* __restrict__ gbR, LvlP P)
{
  const int img = blockIdx.y;
  const int tower = img >> 1, n = img & 1;
  const int e = blockIdx.x * 256 + threadIdx.x;
  const int pos = e >> 5;
  const int g = e & 31;
  if (pos >= TOTROW) return;
  const int l = (pos >= P.roff[1]) + (pos >= P.roff[2]) + (pos >= P.roff[3]) + (pos >= P.roff[4]);
  const int W = sel5i(P.W, l);
  const int local = pos - sel5i(P.roff, l);
  const int y = local / W, x = local - y * W;
  const size_t dst = ((size_t)n * PTOT + sel5i(P.poff, l) + (y + 1) * (W + 2) + (x + 1)) * 256 + g * 8;
  const size_t srco = ((size_t)n * TOTROW + pos) * 256 + g * 8;
  const unsigned short* Y = (tower ? Yr : Yc) + srco;
  unsigned short* X = (tower ? Xr : Xc) + dst;
  const float* gw = (tower ? gwR : gwC) + g * 8;
  const float* gb = (tower ? gbR : gbC) + g * 8;
  const float* st = stats + (((size_t)l * 4 + img) * 32 + g) * 2;
  const float inv = sel5f(P.inv8HW, l);
  const float m = st[0] * inv;
  const float var = st[1] * inv - m * m;
  const float rs = rsqrtf(var + 1e-5f);
  ushortx8 yv = *(const ushortx8*)Y;
  ushortx8 xv;
#pragma unroll
  for (int j = 0; j < 8; ++j) {
    const float yj = bf2f(yv[j]);
    const float v = (yj - m) * rs * gw[j] + gb[j];
    xv[j] = f2bf(fmaxf(v, 0.f));
  }
  *(ushortx8*)X = xv;
}

// ---------------------------------------------------------------------------
// Head epilogue, merged levels: Yh [n][21330][128] bf16 -> out [n][21330][84]
// ---------------------------------------------------------------------------
__global__ __launch_bounds__(256) void head_epi(
    const unsigned short* __restrict__ Yh, float* __restrict__ out,
    const float* __restrict__ scales, LvlP P)
{
  const int n = blockIdx.y;
  const int e = blockIdx.x * 256 + threadIdx.x;
  if (e >= TOTROW * 84) return;
  const int pos = e / 84;
  const int j = e - pos * 84;
  const int l = (pos >= P.roff[1]) + (pos >= P.roff[2]) + (pos >= P.roff[3]) + (pos >= P.roff[4]);
  const unsigned short* yp = Yh + ((size_t)n * TOTROW + pos) * 128;
  float v;
  if (j < 80) {
    const float lg = bf2f(yp[j]);
    const float ct = bf2f(yp[80]);
    v = (1.f / (1.f + __expf(-lg))) * (1.f / (1.f + __expf(-ct)));
  } else {
    const int d = j - 80;
    const float stride = sel5f(P.strd, l);
    const int W = sel5i(P.W, l);
    const int local = pos - sel5i(P.roff, l);
    const int gy = local / W, gx = local - gy * W;
    const float pv = bf2f(yp[81 + d]);
    const float rg = fmaxf(pv * scales[l], 0.f) * stride;
    const float sx = gx * stride, sy = gy * stride;
    v = (d == 0) ? sx - rg : (d == 1) ? sy - rg : (d == 2) ? sx + rg : sy + rg;
  }
  out[((size_t)n * TOTROW + pos) * 84 + j] = v;
}

// ---------------------------------------------------------------------------
extern "C" void kernel_launch(void* const* d_in, const int* in_sizes, int n_in,
                              void* d_out, int out_size, void* d_ws, size_t ws_size,
                              hipStream_t stream)
{
  (void)in_sizes; (void)n_in; (void)out_size; (void)ws_size;

  const float* feats[5];
  for (int l = 0; l < 5; ++l) feats[l] = (const float*)d_in[l];
  const float* cls_w  = (const float*)d_in[5];
  const float* cls_b  = (const float*)d_in[6];
  const float* cls_gw = (const float*)d_in[7];
  const float* cls_gb = (const float*)d_in[8];
  const float* box_w  = (const float*)d_in[9];
  const float* box_b  = (const float*)d_in[10];
  const float* box_gw = (const float*)d_in[11];
  const float* box_gb = (const float*)d_in[12];
  const float* score_w = (const float*)d_in[13];
  const float* score_b = (const float*)d_in[14];
  const float* pred_w  = (const float*)d_in[15];
  const float* pred_b  = (const float*)d_in[16];
  const float* ctr_w   = (const float*)d_in[17];
  const float* ctr_b   = (const float*)d_in[18];
  const float* scales  = (const float*)d_in[19];
  float* out = (float*)d_out;

  static const int Hs[5] = {100, 50, 25, 13, 7};
  static const int Ws[5] = {160, 80, 40, 20, 10};
  LvlP P;
  {
    static const int to[6] = {0, 45, 60, 66, 68, 69};   // 32x12 tiles
    static const int tX[5] = {5, 3, 2, 1, 1};
    static const int po[5] = {0, 16524, 20788, 21922, 22252};
    static const int pe[5] = {16524, 20788, 21922, 22252, 22360};
    static const int ro[6] = {0, 16000, 20000, 21000, 21260, 21330};
    for (int i = 0; i < 6; ++i) { P.tileoff[i] = to[i]; P.roff[i] = ro[i]; }
    for (int i = 0; i < 5; ++i) {
      P.tilesX[i] = tX[i]; P.H[i] = Hs[i]; P.W[i] = Ws[i];
      P.poff[i] = po[i]; P.pend[i] = pe[i];
      P.inv8HW[i] = 1.f / (8.f * Hs[i] * Ws[i]);
      P.strd[i] = (float)(8 << i);
    }
  }

  char* p = (char*)d_ws;
  auto alloc = [&](size_t bytes) {
    char* r = p;
    p += (bytes + 255) & ~(size_t)255;
    return r;
  };
  const size_t XPAD = (size_t)2 * PTOT * 256 * 2;
  const size_t YSZ  = (size_t)2 * TOTROW * 256 * 2;
  unsigned short* Xf  = (unsigned short*)alloc(XPAD);
  unsigned short* Xc  = (unsigned short*)alloc(XPAD);
  unsigned short* Xr  = (unsigned short*)alloc(XPAD);
  unsigned short* Yc  = (unsigned short*)alloc(YSZ);
  unsigned short* Yr  = (unsigned short*)alloc(YSZ);
  unsigned short* Yh  = (unsigned short*)alloc((size_t)2 * TOTROW * 128 * 2);
  unsigned short* wtC = (unsigned short*)alloc(4718592);
  unsigned short* wtR = (unsigned short*)alloc(4718592);
  unsigned short* wth = (unsigned short*)alloc(1179648);
  float* bh    = (float*)alloc(512);
  float* stats = (float*)alloc(4 * 5 * 4 * 32 * 2 * sizeof(float));

  hipMemsetAsync(Xf, 0, XPAD, stream);
  hipMemsetAsync(Xc, 0, XPAD, stream);
  hipMemsetAsync(Xr, 0, XPAD, stream);
  hipMemsetAsync(stats, 0, 4 * 5 * 4 * 32 * 2 * sizeof(float), stream);

  prep_tower_w<<<9216, 256, 0, stream>>>(cls_w, box_w, wtC, wtR);
  prep_head_w<<<2304, 256, 0, stream>>>(score_w, score_b, ctr_w, ctr_b,
                                        pred_w, pred_b, wth, bh);
  for (int l = 0; l < 5; ++l) {
    const int HW = Hs[l] * Ws[l];
    to_chlast<<<dim3((HW + 63) / 64, 8), 256, 0, stream>>>(
        feats[l], Xf, HW, Ws[l], P.poff[l]);
  }

  for (int i = 0; i < 4; ++i) {
    const unsigned short* ic_ = (i == 0) ? Xf : Xc;
    const unsigned short* ir_ = (i == 0) ? Xf : Xr;
    float* st = stats + (size_t)i * 5 * 4 * 32 * 2;
    conv_mfma<<<dim3(69, 4, 4), 256, 0, stream>>>(
        ic_, ir_, Yc, Yr,
        wtC + (size_t)i * 589824, wtR + (size_t)i * 589824,
        cls_b + i * 256, box_b + i * 256, st, P, 1, 256);
    gn_apply<<<dim3((TOTROW * 32 + 255) / 256, 4), 256, 0, stream>>>(
        Yc, Yr, Xc, Xr, st,
        cls_gw + i * 256, cls_gb + i * 256,
        box_gw + i * 256, box_gb + i * 256, P);
  }

  conv_mfma<<<dim3(69, 2, 2), 256, 0, stream>>>(
      Xc, Xr, Yh, nullptr, wth, nullptr, bh, nullptr, nullptr, P, 2, 128);
  head_epi<<<dim3((TOTROW * 84 + 255) / 256, 2), 256, 0, stream>>>(
      Yh, out, scales, P);
}